// Round 4
// baseline (112.304 us; speedup 1.0000x reference)
//
#include <hip/hip_runtime.h>

#define NQ     14
#define DIMQ   16384
#define NTROT  10
#define NWG    16
#define NTHR   256

struct Smem {
    float2 slab[1024];   // 8 KiB per-WG staging slab (one coset)
    float2 tabLo[64];    // e^{i phi} for ZZ couplers 0..5
    float2 tabHi[128];   // e^{i phi} for ZZ couplers 6..12
    float  red[48];      // this WG's partial sums of the 42 constants
};

// ---------- device-coherent (cross-XCD) accessors: sc0 sc1, bypass L1/L2 ----
__device__ __forceinline__ float2 cload2(const float2* p) {
    union { unsigned long long u; float2 f; } x;
    x.u = __hip_atomic_load((const unsigned long long*)p,
                            __ATOMIC_RELAXED, __HIP_MEMORY_SCOPE_AGENT);
    return x.f;
}
__device__ __forceinline__ void cstore2(float2* p, float2 v) {
    union { unsigned long long u; float2 f; } x;
    x.f = v;
    __hip_atomic_store((unsigned long long*)p, x.u,
                       __ATOMIC_RELAXED, __HIP_MEMORY_SCOPE_AGENT);
}
__device__ __forceinline__ float cloadf(const float* p) {
    return __hip_atomic_load(p, __ATOMIC_RELAXED, __HIP_MEMORY_SCOPE_AGENT);
}
__device__ __forceinline__ void cstoref(float* p, float v) {
    __hip_atomic_store(p, v, __ATOMIC_RELAXED, __HIP_MEMORY_SCOPE_AGENT);
}

// Flag-array barrier: arrival = plain coherent store to own slot (no RMW
// serialization); poll = ONE coalesced coherent load of all 16 flags by wave
// 0's lanes 0..15 + ballot. Flags carry the phase number, monotonically
// increasing, so the 0xAA poison (negative int) means "not arrived" and no
// zero-init is needed. __syncthreads() before arrival drains each wave's
// vmcnt, so all sc1 psi stores are device-visible before the flag store.
__device__ __forceinline__ void gbar(int* flags, int w, int phase) {
    __syncthreads();
    if (threadIdx.x < 64) {
        if (threadIdx.x == 0)
            __hip_atomic_store(&flags[w], phase,
                               __ATOMIC_RELAXED, __HIP_MEMORY_SCOPE_AGENT);
        for (;;) {
            int v = phase;
            if (threadIdx.x < NWG)
                v = __hip_atomic_load(&flags[threadIdx.x],
                                      __ATOMIC_RELAXED, __HIP_MEMORY_SCOPE_AGENT);
            if (__ballot(v >= phase) == ~0ull) break;
            __builtin_amdgcn_s_sleep(1);
        }
    }
    __syncthreads();
}

// ---------------------------------------------------------------------------
__device__ __forceinline__ float2 cmulf(float2 a, float2 b) {
    return make_float2(a.x * b.x - a.y * b.y, a.x * b.y + a.y * b.x);
}
__device__ __forceinline__ void bfly(float2& p0, float2& p1, float c, float s) {
    float2 n0 = make_float2(c * p0.x + s * p1.y, c * p0.y - s * p1.x);
    float2 n1 = make_float2(c * p1.x + s * p0.y, c * p1.y - s * p0.x);
    p0 = n0; p1 = n1;
}
__device__ __forceinline__ void bfly_shfl(float2& p, int mask, float c, float s) {
    float qx = __shfl_xor(p.x, mask);
    float qy = __shfl_xor(p.y, mask);
    p = make_float2(c * p.x + s * qy, c * p.y - s * qx);
}
__device__ __forceinline__ void zz_apply(const Smem& sm, float2& a, int k) {
    int d = (k ^ (k >> 1)) & 0x1FFF;
    float2 rot = cmulf(sm.tabLo[d & 63], sm.tabHi[d >> 6]);
    a = cmulf(a, rot);
}
__device__ __forceinline__ void stage_12(float2* slab, float2 r[4], int t) {
    __syncthreads();
#pragma unroll
    for (int j = 0; j < 4; ++j) slab[(t << 2) | j] = r[j];
    __syncthreads();
#pragma unroll
    for (int j = 0; j < 4; ++j) r[j] = slab[t | (j << 8)];
}
__device__ __forceinline__ void stage_21(float2* slab, float2 r[4], int t) {
    __syncthreads();
#pragma unroll
    for (int j = 0; j < 4; ++j) slab[t | (j << 8)] = r[j];
    __syncthreads();
#pragma unroll
    for (int j = 0; j < 4; ++j) r[j] = slab[(t << 2) | j];
}

// Reduce expectation triple i over the WG's slab; qubit sits at slab bit sb.
__device__ __forceinline__ void reduce_qubit(Smem& sm, int sb, int i, int t) {
    float cr = 0.f, ci = 0.f, z = 0.f;
#pragma unroll
    for (int j = 0; j < 4; ++j) {
        const int m = (t << 2) | j;
        const float2 a = sm.slab[m];
        const float n = a.x * a.x + a.y * a.y;
        if ((m >> sb) & 1) {
            z -= n;
        } else {
            z += n;
            const float2 b = sm.slab[m ^ (1 << sb)];
            cr += a.x * b.x + a.y * b.y;
            ci += a.x * b.y - a.y * b.x;
        }
    }
#pragma unroll
    for (int off = 32; off; off >>= 1) {
        cr += __shfl_down(cr, off);
        ci += __shfl_down(ci, off);
        z  += __shfl_down(z, off);
    }
    if ((t & 63) == 0) {
        atomicAdd(&sm.red[3 * i + 0], cr);
        atomicAdd(&sm.red[3 * i + 1], ci);
        atomicAdd(&sm.red[3 * i + 2], z);
    }
}

// Layout A: k = (w<<10)|m, slab bit b == qubit b (WG w = qubits 10..13).
template <bool FIRST>
__device__ void phaseA(Smem& sm, float2* psi, int w, int t,
                       const float* c, const float* s) {
    float2 r[4];
    if (FIRST) {
#pragma unroll
        for (int j = 0; j < 4; ++j) r[j] = make_float2(0.0078125f, 0.0f);
    } else {
#pragma unroll
        for (int j = 0; j < 4; ++j) r[j] = cload2(&psi[(w << 10) | (t << 2) | j]);
        // leftover RX_s{0..3}
        bfly(r[0], r[1], c[0], s[0]); bfly(r[2], r[3], c[0], s[0]);
        bfly(r[0], r[2], c[1], s[1]); bfly(r[1], r[3], c[1], s[1]);
#pragma unroll
        for (int j = 0; j < 4; ++j) bfly_shfl(r[j], 1, c[2], s[2]);
#pragma unroll
        for (int j = 0; j < 4; ++j) bfly_shfl(r[j], 2, c[3], s[3]);
    }
    // ZZ_{s+1} + RX_{s+1}{0..9}
#pragma unroll
    for (int j = 0; j < 4; ++j) zz_apply(sm, r[j], (w << 10) | (t << 2) | j);
    bfly(r[0], r[1], c[0], s[0]); bfly(r[2], r[3], c[0], s[0]);
    bfly(r[0], r[2], c[1], s[1]); bfly(r[1], r[3], c[1], s[1]);
#pragma unroll
    for (int b = 0; b < 6; ++b) {
#pragma unroll
        for (int j = 0; j < 4; ++j) bfly_shfl(r[j], 1 << b, c[2 + b], s[2 + b]);
    }
    stage_12(sm.slab, r, t);   // reg bits now = qubits 8,9
    bfly(r[0], r[1], c[8], s[8]); bfly(r[2], r[3], c[8], s[8]);
    bfly(r[0], r[2], c[9], s[9]); bfly(r[1], r[3], c[9], s[9]);
#pragma unroll
    for (int j = 0; j < 4; ++j) cstore2(&psi[(w << 10) | t | (j << 8)], r[j]);
}

// Layout B: k = (m<<4)|w, slab bit b == qubit b+4 (WG w = qubits 0..3).
// RX_s{10..13}, ZZ_{s+1}, RX_{s+1}{4..13}. If REDUCE: also the q=10..13
// expectations into sm.red (valid: remaining RX_{s+1}{0..3} commutes).
template <bool REDUCE>
__device__ void phaseB(Smem& sm, float2* psi, int w, int t,
                       const float* c, const float* s) {
    float2 r[4];
#pragma unroll
    for (int j = 0; j < 4; ++j) r[j] = cload2(&psi[(((t << 2) | j) << 4) | w]);
#pragma unroll
    for (int j = 0; j < 4; ++j) bfly_shfl(r[j], 16, c[10], s[10]);
#pragma unroll
    for (int j = 0; j < 4; ++j) bfly_shfl(r[j], 32, c[11], s[11]);
    stage_12(sm.slab, r, t);       // reg bits now = qubits 12,13
    bfly(r[0], r[1], c[12], s[12]); bfly(r[2], r[3], c[12], s[12]);
    bfly(r[0], r[2], c[13], s[13]); bfly(r[1], r[3], c[13], s[13]);
#pragma unroll
    for (int j = 0; j < 4; ++j) zz_apply(sm, r[j], ((t | (j << 8)) << 4) | w);
    bfly(r[0], r[1], c[12], s[12]); bfly(r[2], r[3], c[12], s[12]);
    bfly(r[0], r[2], c[13], s[13]); bfly(r[1], r[3], c[13], s[13]);
#pragma unroll
    for (int b = 0; b < 6; ++b) {
#pragma unroll
        for (int j = 0; j < 4; ++j) bfly_shfl(r[j], 1 << b, c[4 + b], s[4 + b]);
    }
    stage_21(sm.slab, r, t);       // back to mapping1 (regs = qubits 4,5)
#pragma unroll
    for (int j = 0; j < 4; ++j) bfly_shfl(r[j], 16, c[10], s[10]);
#pragma unroll
    for (int j = 0; j < 4; ++j) bfly_shfl(r[j], 32, c[11], s[11]);
#pragma unroll
    for (int j = 0; j < 4; ++j) cstore2(&psi[(((t << 2) | j) << 4) | w], r[j]);

    if (REDUCE) {
        // slab[(t<<2)|j] was last read by this same thread in stage_21 — safe
#pragma unroll
        for (int j = 0; j < 4; ++j) sm.slab[(t << 2) | j] = r[j];
        __syncthreads();
        // qubit q at slab bit q-4; triple i = 13-q → sm.red[0..11]
#pragma unroll
        for (int q = 10; q <= 13; ++q) reduce_qubit(sm, q - 4, 13 - q, t);
    }
}

// Final phase (layout A): leftover RX_10{0..3}, then q=0..9 expectations into
// sm.red[12..41]; store all 42 partials to this WG's slot. No psi write-back.
__device__ void phaseA_final(Smem& sm, const float2* psi, int w, int t,
                             const float* c, const float* s, float* partials) {
    float2 r[4];
#pragma unroll
    for (int j = 0; j < 4; ++j) r[j] = cload2(&psi[(w << 10) | (t << 2) | j]);
    bfly(r[0], r[1], c[0], s[0]); bfly(r[2], r[3], c[0], s[0]);
    bfly(r[0], r[2], c[1], s[1]); bfly(r[1], r[3], c[1], s[1]);
#pragma unroll
    for (int j = 0; j < 4; ++j) bfly_shfl(r[j], 1, c[2], s[2]);
#pragma unroll
    for (int j = 0; j < 4; ++j) bfly_shfl(r[j], 2, c[3], s[3]);
    __syncthreads();
#pragma unroll
    for (int j = 0; j < 4; ++j) sm.slab[(t << 2) | j] = r[j];
    __syncthreads();
#pragma unroll
    for (int q = 0; q <= 9; ++q) reduce_qubit(sm, q, 13 - q, t);
    __syncthreads();
    if (t < 42) cstoref(&partials[w * 48 + t], sm.red[t]);
}

extern "C" __global__ void __launch_bounds__(NTHR)
qr_all(const float* __restrict__ x, const float* __restrict__ J,
       const float* __restrict__ g, float* __restrict__ out,
       float2* __restrict__ psi, float* __restrict__ partials,
       int* __restrict__ flags) {
    __shared__ Smem sm;
    const int w = blockIdx.x;
    const int t = threadIdx.x;
    const float dt = 0.1f;   // EVO_TIME / N_TROTTER

    if (t < 64) {
        float phi = 0.0f;
        for (int i = 0; i < 6; ++i) {
            const float h = 0.5f * J[i] * dt;
            phi += ((t >> i) & 1) ? h : -h;
        }
        float sn, cs; __sincosf(phi, &sn, &cs);
        sm.tabLo[t] = make_float2(cs, sn);
    } else if (t < 192) {
        const int v = t - 64;
        float phi = 0.0f;
        for (int i = 0; i < 7; ++i) {
            const float h = 0.5f * J[6 + i] * dt;
            phi += ((v >> i) & 1) ? h : -h;
        }
        float sn, cs; __sincosf(phi, &sn, &cs);
        sm.tabHi[v] = make_float2(cs, sn);
    }
    if (t < 48) sm.red[t] = 0.0f;
    float cc[NQ], ss[NQ];
#pragma unroll
    for (int i = 0; i < NQ; ++i) __sincosf(0.5f * g[i] * dt, &ss[i], &cc[i]);
    __syncthreads();

    int bar = 0;
    // Phase 1 (A): init + ZZ_1 + RX_1{0..9}
    phaseA<true>(sm, psi, w, t, cc, ss);
    gbar(flags, w, ++bar);
    // Phases 2..10
    for (int sstep = 1; sstep <= 9; ++sstep) {
        if (sstep & 1) {
            if (sstep == 9) phaseB<true >(sm, psi, w, t, cc, ss);
            else            phaseB<false>(sm, psi, w, t, cc, ss);
        } else {
            phaseA<false>(sm, psi, w, t, cc, ss);
        }
        gbar(flags, w, ++bar);
    }
    // Phase 11 (A): leftover RX_10{0..3} + reductions q0..9 + partial store
    phaseA_final(sm, psi, w, t, cc, ss, partials);
    gbar(flags, w, ++bar);

    // Epilogue: sum the 16 per-WG partials into LDS, then batched outputs
    if (t < 42) {
        float sum = 0.0f;
#pragma unroll
        for (int w2 = 0; w2 < NWG; ++w2) sum += cloadf(&partials[w2 * 48 + t]);
        sm.red[t] = sum;
    }
    __syncthreads();
    const int gtid = w * NTHR + t;
    for (int task = gtid; task < 2048 * NQ; task += NWG * NTHR) {
        const int b = task / NQ;
        const int i = task - b * NQ;
        const int q = 13 - i;
        const float xv = x[b * NQ + q];
        const float cr = sm.red[3 * i + 0];
        const float ci = sm.red[3 * i + 1];
        const float zz = sm.red[3 * i + 2];
        float sn, cs; __sincosf(xv, &sn, &cs);
        float* o = out + b * (3 * NQ) + 3 * i;
        o[0] = 2.0f * (cs * cr - sn * ci);
        o[1] = 2.0f * (sn * cr + cs * ci);
        o[2] = zz;
    }
}

extern "C" void kernel_launch(void* const* d_in, const int* in_sizes, int n_in,
                              void* d_out, int out_size, void* d_ws, size_t ws_size,
                              hipStream_t stream) {
    const float* x = (const float*)d_in[0];
    const float* J = (const float*)d_in[1];
    const float* g = (const float*)d_in[2];
    float* out      = (float*)d_out;
    float2* psi     = (float2*)d_ws;                                   // 128 KiB
    int*   flags    = (int*)((char*)d_ws + DIMQ * sizeof(float2));     // 16 ints, own line
    float* partials = (float*)((char*)d_ws + DIMQ * sizeof(float2) + 256); // 16*48 floats
    (void)in_sizes; (void)n_in; (void)out_size; (void)ws_size;

    // No memset needed: flags are phase-numbered (poison 0xAA... is negative =
    // "not arrived"), partials are fully overwritten before being read.
    hipLaunchKernelGGL(qr_all, dim3(NWG), dim3(NTHR), 0, stream,
                       x, J, g, out, psi, partials, flags);
}